// Round 8
// baseline (68.629 us; speedup 1.0000x reference)
//
#include <hip/hip_runtime.h>

// SOMFNN forward, MI355X. Round 8: R7 + one-line fix.
//
// R7 post-mortem: K3 staged only 16 f32x4 of s_xi (one row) instead of 64
// (four rows) -> yn for rows i0+1..i0+3 was sigmoid(LDS garbage). Same bug
// was in R6's K3, so R6's failure is also explained (d_ws-size theory was
// untested). Fix: `if (t < 64)` on the x staging. All else identical to R7.
//
// Math (verified rounds 1,2,4,5: absmax 0.0): every scan step creates a rule;
// final state protos = cents = x, senc = sen, n = M. Then
//   stau = |g_term|/2 ; d2[r,i] = sen_i + ||x_r||^2 - 2 x_r.x_i
//   dens = exp(-max(d2,0)/stau) ; lambda = dens/colsum
//   y[i, r*64+o] = lambda[r,i]*sigmoid(xW^T+b)[i,o]
//
// K1: -1/stau (1 block).                     ~2-3 us
// K2: densT rows + per-tile col partials, staged in d_out row regions. ~2 us
// K3: pure store stream, tiny preamble.      ~41-44 us (write-bound)

typedef float f32x4 __attribute__((ext_vector_type(4)));

#define ROWF 65536            // floats per output row region
#define POFF 1024             // partials offset within row region

// ---- K1: ws[0] = -1/stau ----
__global__ __launch_bounds__(1024) void somfnn_stats(
    const float* __restrict__ x, float* __restrict__ ws) {
  __shared__ float s_part[16][64];
  __shared__ float s_wssq[16];
  const int t = threadIdx.x, c = t & 63, g = t >> 6;

  float cs = 0.f, ssq = 0.f;
  const float* xp = x + g * 64 + c;
#pragma unroll 8
  for (int k = 0; k < 64; ++k) {
    float v = xp[(size_t)k * 16 * 64];
    cs += v;
    ssq += v * v;
  }
  s_part[g][c] = cs;
#pragma unroll
  for (int s = 1; s < 64; s <<= 1) ssq += __shfl_xor(ssq, s);
  if (c == 0) s_wssq[g] = ssq;
  __syncthreads();
  if (t < 64) {
    float col = 0.f;
#pragma unroll
    for (int gg = 0; gg < 16; ++gg) col += s_part[gg][t];
    float gm = col * (1.0f / 1024.0f) * (1.0f / 1024.0f);
    float g2 = gm * gm;
#pragma unroll
    for (int s = 1; s < 64; s <<= 1) g2 += __shfl_xor(g2, s);
    if (t == 0) {
      float tssq = 0.f;
#pragma unroll
      for (int gg = 0; gg < 16; ++gg) tssq += s_wssq[gg];
      float gsm = tssq * (1.0f / 1024.0f) * (1.0f / 1024.0f);
      float g_term = gsm - g2;
      ws[0] = -1.0f / (fabsf(g_term) * 0.5f);
    }
  }
}

// ---- K2: dens tile (rt,it), 64x64 per block, 4x4 per thread ----
// Writes densT[i][r0..r0+3] into out[i*ROWF + r0] and the tile's column
// partial sum into out[i*ROWF + POFF + rt].
__global__ __launch_bounds__(256) void somfnn_dens(
    const float* __restrict__ x, const float* __restrict__ ws,
    float* __restrict__ out) {
  __shared__ float s_xi[64 * 68];    // Xi tile, padded row stride
  __shared__ float s_seni[64];
  const int t = threadIdx.x;
  const int rt = blockIdx.x & 15, it = blockIdx.x >> 4;

  const f32x4* xg = (const f32x4*)x;
  {
    const int base = it * 64 * 16;   // f4 units
#pragma unroll
    for (int k = 0; k < 4; ++k) {
      const int f = t + 256 * k;
      const int row = f >> 4, col = f & 15;
      f32x4 v = xg[base + f];
      ((f32x4*)(s_xi + row * 68))[col] = v;
      float p = v.x * v.x + v.y * v.y + v.z * v.z + v.w * v.w;
#pragma unroll
      for (int s = 1; s < 16; s <<= 1) p += __shfl_xor(p, s);
      if ((t & 15) == 0) s_seni[row] = p;
    }
  }
  __syncthreads();

  const float ninv = ws[0];
  const int rg = t & 15, ig = t >> 4;
  const int r0 = rt * 64 + rg * 4;
  const int iL0 = ig * 4;

  float acc[4][4], sq[4] = {0.f, 0.f, 0.f, 0.f};
#pragma unroll
  for (int a = 0; a < 4; ++a)
#pragma unroll
    for (int b = 0; b < 4; ++b) acc[a][b] = 0.f;

#pragma unroll
  for (int q = 0; q < 16; ++q) {
    f32x4 u[4];
#pragma unroll
    for (int b = 0; b < 4; ++b)
      u[b] = ((const f32x4*)(s_xi + (iL0 + b) * 68))[q];
#pragma unroll
    for (int a = 0; a < 4; ++a) {
      f32x4 v = xg[(size_t)(r0 + a) * 16 + q];
      sq[a] += v.x * v.x + v.y * v.y + v.z * v.z + v.w * v.w;
#pragma unroll
      for (int b = 0; b < 4; ++b)
        acc[a][b] += v.x * u[b].x + v.y * u[b].y + v.z * u[b].z + v.w * u[b].w;
    }
  }

#pragma unroll
  for (int b = 0; b < 4; ++b) {
    const int i = it * 64 + iL0 + b;
    const float seni = s_seni[iL0 + b];
    float e0 = expf(fmaxf(seni + sq[0] - 2.f * acc[0][b], 0.f) * ninv);
    float e1 = expf(fmaxf(seni + sq[1] - 2.f * acc[1][b], 0.f) * ninv);
    float e2 = expf(fmaxf(seni + sq[2] - 2.f * acc[2][b], 0.f) * ninv);
    float e3 = expf(fmaxf(seni + sq[3] - 2.f * acc[3][b], 0.f) * ninv);
    f32x4 dv = {e0, e1, e2, e3};
    *(f32x4*)(out + (size_t)i * ROWF + r0) = dv;
    float csum = (e0 + e1) + (e2 + e3);
#pragma unroll
    for (int s = 1; s < 16; s <<= 1) csum += __shfl_xor(csum, s);
    if (rg == 0) out[(size_t)i * ROWF + POFF + rt] = csum;
  }
}

// ---- K3: store stream, 4 rows per block; reads only its own row regions ----
__global__ __launch_bounds__(256) void somfnn_store(
    const float* __restrict__ x, const float* __restrict__ W,
    const float* __restrict__ bias, float* __restrict__ out) {
  __shared__ float s_lam[4][1024];   // raw dens rows, 16 KB
  __shared__ float s_xi[4][64];
  __shared__ float s_yn[4][64];
  __shared__ float s_pc[4][16];
  __shared__ float s_inv[4];

  const int t = threadIdx.x;
  const int wv = t >> 6, ln = t & 63;
  const int i0 = blockIdx.x * 4;

  // stage 4 dens rows (own regions only) + partials + x rows (64 f32x4!)
#pragma unroll
  for (int k = 0; k < 4; ++k) {
    const int f = t + 256 * k;       // f4 index over 4 rows x 256
    const int row = f >> 8, r4 = f & 255;
    ((f32x4*)s_lam[row])[r4] =
        *(const f32x4*)(out + (size_t)(i0 + row) * ROWF + r4 * 4);
  }
  if (t < 64) {
    s_pc[t >> 4][t & 15] = out[(size_t)(i0 + (t >> 4)) * ROWF + POFF + (t & 15)];
    ((f32x4*)s_xi)[t] = ((const f32x4*)(x + (size_t)i0 * 64))[t];  // 4 rows
  }
  __syncthreads();

  if (t < 4) {
    float c = 0.f;
#pragma unroll
    for (int rt = 0; rt < 16; ++rt) c += s_pc[t][rt];
    s_inv[t] = 1.0f / c;
  }
  // yn: wave wv computes row wv's 64 sigmoids
  {
    const f32x4* wr = (const f32x4*)(W + ln * 64);
    float acc = bias[ln];
#pragma unroll
    for (int q = 0; q < 16; ++q) {
      f32x4 w4 = wr[q], u = ((const f32x4*)s_xi[wv])[q];
      acc += w4.x * u.x + w4.y * u.y + w4.z * u.z + w4.w * u.w;
    }
    s_yn[wv][ln] = 1.0f / (1.0f + expf(-acc));
  }
  __syncthreads();

  // store: 4 contiguous 256 KB rows; r = iter*16 + (t>>4), o4 = t&15
  const int rb = t >> 4, c4 = t & 15;
#pragma unroll
  for (int i = 0; i < 4; ++i) {
    const f32x4 yn4 = ((const f32x4*)s_yn[i])[c4] * s_inv[i];
    f32x4* orow = (f32x4*)(out + (size_t)(i0 + i) * ROWF);
#pragma unroll 8
    for (int iter = 0; iter < 64; ++iter) {
      orow[iter * 256 + t] = yn4 * s_lam[i][iter * 16 + rb];
    }
  }
}

extern "C" void kernel_launch(void* const* d_in, const int* in_sizes, int n_in,
                              void* d_out, int out_size, void* d_ws, size_t ws_size,
                              hipStream_t stream) {
  const float* x = (const float*)d_in[0];
  const float* W = (const float*)d_in[1];
  const float* b = (const float*)d_in[2];
  float* out = (float*)d_out;
  float* ws  = (float*)d_ws;   // uses 4 bytes

  somfnn_stats<<<1, 1024, 0, stream>>>(x, ws);
  somfnn_dens<<<256, 256, 0, stream>>>(x, ws, out);
  somfnn_store<<<256, 256, 0, stream>>>(x, W, b, out);
}